// Round 18
// baseline (139.762 us; speedup 1.0000x reference)
//
#include <hip/hip_runtime.h>

#define NS   16
#define NV   4
#define FEAT 48          // N_EDGE_FEAT
#define WN   320         // W_NUMEL
#define MSG  28          // logical message width (fp32 out)
#define MSGB 32          // bf16 msg row stride (elements) -> 64 B rows

typedef __bf16 bf16x8 __attribute__((ext_vector_type(8)));
typedef __bf16 bf16x4 __attribute__((ext_vector_type(4)));
typedef float  f32x4  __attribute__((ext_vector_type(4)));

#define PK1_ELEMS (2 * 3 * 64 * 8)    // 3072 bf16
#define PK2_ELEMS (2 * 20 * 64 * 8)   // 20480 bf16
#define PACK_BLOCKS 8

// ---------------- prep: weight packing (blocks 0..7) + histogram WITH positions ----------------
__global__ void prep_kernel(const float* __restrict__ fc1_w, const float* __restrict__ fc1_b,
                            const float* __restrict__ fc2_w, const float* __restrict__ fc2_b,
                            const int* __restrict__ src,
                            __bf16* __restrict__ pk1, __bf16* __restrict__ pk2,
                            int* __restrict__ count, int* __restrict__ pos, int E)
{
    const int tid = threadIdx.x;
    if (blockIdx.x < PACK_BLOCKS) {
        const int idx = blockIdx.x * 256 + tid;
        const int stride = PACK_BLOCKS * 256;
        for (int i = idx; i < PK1_ELEMS; i += stride) {
            const int j = i & 7, l = (i >> 3) & 63, f = i >> 9;   // f = p*3 + nt
            const int nt = f % 3, p = f / 3;
            const int q = l >> 4, col = 16 * nt + (l & 15);
            float v;
            if (p == 0) {
                const int k = (j < 4) ? (4 * q + j) : (16 + 4 * q + j - 4);
                v = fc1_w[k * FEAT + col];
            } else if (j < 4) {
                v = fc1_w[(32 + 4 * q + j) * FEAT + col];
            } else {
                v = (j == 4 && q == 0) ? fc1_b[col] : 0.f;
            }
            pk1[i] = (__bf16)v;
        }
        for (int i = idx; i < PK2_ELEMS; i += stride) {
            const int j = i & 7, l = (i >> 3) & 63, f = i >> 9;   // f = p*20 + nt
            const int nt = f % 20, p = f / 20;
            const int q = l >> 4, col = 16 * nt + (l & 15);
            float v;
            if (p == 0) {
                const int k = (j < 4) ? (4 * q + j) : (16 + 4 * q + j - 4);
                v = fc2_w[k * WN + col];
            } else if (j < 4) {
                v = fc2_w[(32 + 4 * q + j) * WN + col];
            } else {
                v = (j == 4 && q == 0) ? fc2_b[col] : 0.f;
            }
            pk2[i] = (__bf16)v;
        }
    } else {
        const int nb = gridDim.x - PACK_BLOCKS;
        for (int e = (blockIdx.x - PACK_BLOCKS) * 256 + tid; e < E; e += nb * 256)
            pos[e] = atomicAdd(&count[src[e]], 1);
    }
}

// ---------------- single-launch CSR scan: block-local scan + atomic block base ----------------
__global__ void scan_atomic(const int* __restrict__ in, int* __restrict__ outBase,
                            int* __restrict__ gctr, int n)
{
    __shared__ int s[256];
    __shared__ int blockBase;
    const int tid = threadIdx.x;
    const int i = blockIdx.x * 256 + tid;
    int v = (i < n) ? in[i] : 0;
    int acc = v;
    s[tid] = acc;
    __syncthreads();
    #pragma unroll
    for (int off = 1; off < 256; off <<= 1) {
        int t = (tid >= off) ? s[tid - off] : 0;
        __syncthreads();
        acc += t;
        s[tid] = acc;
        __syncthreads();
    }
    if (tid == 255) blockBase = atomicAdd(gctr, acc);
    __syncthreads();
    if (i < n) outBase[i] = blockBase + acc - v;   // absolute exclusive prefix
}

// ---------------- fused edge compute: swapped-operand MFMA, zero atomics, 2-group pipeline ----------------
// r17 structure + software-pipelined gather (T14 issue-early/consume-late): each wave
// does TWO groups of 32 edges; GATHER(g1) is issued between FC1(g0) and FC2(g0), so
// g1's dependent gather chain (~900cy) lands under g0's fc2 (40 MFMA + 160 FMA).
// Unlike r10's NT=4 (all state live -> spill), state retires between groups: eaf dies
// after fc1, w1f reloaded per group (pk1 is L1-hot). Peak live ~76 regs < (256,6)'s 85.
// MODE 0: write bf16 msg row at rank=base[src]+pos[e]. MODE 1: fp32 atomics.
template<int MODE>
__global__ __launch_bounds__(256, 6) void edge_mfma_kernel(
    const float* __restrict__ node_attr,
    const float* __restrict__ edge_attr,
    const float* __restrict__ edge_sh,
    const int*   __restrict__ edge_index,
    const int*   __restrict__ base,    // MODE 0 (absolute)
    const int*   __restrict__ pos,     // MODE 0
    const __bf16* __restrict__ pk1,
    const __bf16* __restrict__ pk2,
    __bf16* __restrict__ msg,      // MODE 0
    float*  __restrict__ out_acc,  // MODE 1
    float*  __restrict__ cnt,      // MODE 1
    int E)
{
    __shared__ float sX[4][64][20];    // wave-private; 2 groups x 32 rows

    const int tid = threadIdx.x;
    const int w   = tid >> 6;
    const int l   = tid & 63;
    const int q   = l >> 4;
    const int r16 = l & 15;
    const int e0  = (blockIdx.x * 4 + w) * 64;    // this wave's 64 edges (2 groups)

    const float4 z4 = make_float4(0.f, 0.f, 0.f, 0.f);
    const float bias1 = (q == 0) ? 1.f : 0.f;

    // ---- gather one group: fills eaf/srcI/rnkQ/sh, writes x rows g*32.. ----
    auto GATHER = [&](int g, bf16x8 (&eaf)[2][2], int (&srcI)[2], int (&rnkQ)[2],
                      float (&sh0)[2], float (&sh1)[2]) {
        #pragma unroll
        for (int t = 0; t < 2; ++t) {
            const int e = e0 + g * 32 + 16 * t + r16;
            const bool ev = (e < E);
            srcI[t] = ev ? edge_index[e] : 0;
            const int dstI = ev ? edge_index[E + e] : 0;

            rnkQ[t] = 0;
            if (MODE == 0 && q == 0 && ev)
                rnkQ[t] = base[srcI[t]] + pos[e];

            float4 ea4 = z4, sa4 = z4, da4 = z4;
            if (ev) {
                ea4 = *reinterpret_cast<const float4*>(edge_attr + (size_t)e * NS + 4 * q);
                sa4 = *reinterpret_cast<const float4*>(node_attr + (size_t)srcI[t] * NS + 4 * q);
                da4 = *reinterpret_cast<const float4*>(node_attr + (size_t)dstI * NS + 4 * q);
            }
            *reinterpret_cast<f32x4*>(&sX[w][g * 32 + 16 * t + r16][4 * q]) =
                f32x4{da4.x, da4.y, da4.z, da4.w};

            bf16x8 f0, f1;
            f0[0]=(__bf16)ea4.x; f0[1]=(__bf16)ea4.y; f0[2]=(__bf16)ea4.z; f0[3]=(__bf16)ea4.w;
            f0[4]=(__bf16)sa4.x; f0[5]=(__bf16)sa4.y; f0[6]=(__bf16)sa4.z; f0[7]=(__bf16)sa4.w;
            f1[0]=(__bf16)da4.x; f1[1]=(__bf16)da4.y; f1[2]=(__bf16)da4.z; f1[3]=(__bf16)da4.w;
            f1[4]=(__bf16)bias1; f1[5]=(__bf16)0.f; f1[6]=(__bf16)0.f; f1[7]=(__bf16)0.f;
            eaf[t][0] = f0;
            eaf[t][1] = f1;
            sh0[t] = ev ? edge_sh[(size_t)e * 9] : 0.f;
            sh1[t] = (ev && q < 3) ? edge_sh[(size_t)e * 9 + 1 + q] : 0.f;
        }
    };

    // ---- fc1 for one group (w1f loaded locally each call: pk1 is L1-hot, keeps regs low) ----
    auto FC1 = [&](bf16x8 (&eaf)[2][2], bf16x8 (&hc)[2][2]) {
        bf16x8 w1f[2][3];
        #pragma unroll
        for (int p = 0; p < 2; ++p)
            #pragma unroll
            for (int nt = 0; nt < 3; ++nt)
                w1f[p][nt] = *reinterpret_cast<const bf16x8*>(pk1 + ((size_t)(p * 3 + nt) * 64 + l) * 8);
        #pragma unroll
        for (int t = 0; t < 2; ++t) {
            f32x4 h0 = {0.f,0.f,0.f,0.f}, h1 = {0.f,0.f,0.f,0.f}, h2 = {0.f,0.f,0.f,0.f};
            h0 = __builtin_amdgcn_mfma_f32_16x16x32_bf16(w1f[0][0], eaf[t][0], h0, 0, 0, 0);
            h0 = __builtin_amdgcn_mfma_f32_16x16x32_bf16(w1f[1][0], eaf[t][1], h0, 0, 0, 0);
            h1 = __builtin_amdgcn_mfma_f32_16x16x32_bf16(w1f[0][1], eaf[t][0], h1, 0, 0, 0);
            h1 = __builtin_amdgcn_mfma_f32_16x16x32_bf16(w1f[1][1], eaf[t][1], h1, 0, 0, 0);
            h2 = __builtin_amdgcn_mfma_f32_16x16x32_bf16(w1f[0][2], eaf[t][0], h2, 0, 0, 0);
            h2 = __builtin_amdgcn_mfma_f32_16x16x32_bf16(w1f[1][2], eaf[t][1], h2, 0, 0, 0);
            bf16x8 c0, c1;
            #pragma unroll
            for (int g = 0; g < 4; ++g) {
                c0[g]     = (__bf16)fmaxf(h0[g], 0.f);
                c0[4 + g] = (__bf16)fmaxf(h1[g], 0.f);
                c1[g]     = (__bf16)fmaxf(h2[g], 0.f);
            }
            c1[4] = (__bf16)bias1;
            c1[5] = (__bf16)0.f; c1[6] = (__bf16)0.f; c1[7] = (__bf16)0.f;
            hc[t][0] = c0;
            hc[t][1] = c1;
        }
    };

    // ---- fc2 + tensor product + output for one group ----
    auto FC2W = [&](int g, bf16x8 (&hc)[2][2], int (&srcI)[2], int (&rnkQ)[2],
                    float (&sh0)[2], float (&sh1)[2]) {
        f32x4 acc0[2] = {{0.f,0.f,0.f,0.f},{0.f,0.f,0.f,0.f}};
        f32x4 acc1[2] = {{0.f,0.f,0.f,0.f},{0.f,0.f,0.f,0.f}};
        #pragma unroll 4
        for (int nt2 = 0; nt2 < 20; ++nt2) {
            const bf16x8 wf0 = *reinterpret_cast<const bf16x8*>(pk2 + ((size_t)(0 * 20 + nt2) * 64 + l) * 8);
            const bf16x8 wf1 = *reinterpret_cast<const bf16x8*>(pk2 + ((size_t)(1 * 20 + nt2) * 64 + l) * 8);
            #pragma unroll
            for (int t = 0; t < 2; ++t) {
                f32x4 d = {0.f,0.f,0.f,0.f};
                d = __builtin_amdgcn_mfma_f32_16x16x32_bf16(wf0, hc[t][0], d, 0, 0, 0);
                d = __builtin_amdgcn_mfma_f32_16x16x32_bf16(wf1, hc[t][1], d, 0, 0, 0);
                if (nt2 < 16) {
                    const float xv = sX[w][g * 32 + 16 * t + r16][nt2];
                    #pragma unroll
                    for (int gg = 0; gg < 4; ++gg) acc0[t][gg] = fmaf(xv, d[gg], acc0[t][gg]);
                } else {
                    const float xu = sX[w][g * 32 + 16 * t + r16][4 * (nt2 - 16) + q];
                    #pragma unroll
                    for (int gg = 0; gg < 4; ++gg) acc1[t][gg] = fmaf(xu, d[gg], acc1[t][gg]);
                }
            }
        }

        const float inv = 0.25f;   // 1/sqrt(16)

        #pragma unroll
        for (int t = 0; t < 2; ++t)
            #pragma unroll
            for (int gg = 0; gg < 4; ++gg) {
                float s = acc1[t][gg];
                s += __shfl_xor(s, 16);
                s += __shfl_xor(s, 32);
                acc1[t][gg] = s;
            }

        #pragma unroll
        for (int t = 0; t < 2; ++t) {
            const int e = e0 + g * 32 + 16 * t + r16;
            if (e >= E) continue;
            if (MODE == 0) {
                const int rnk = __shfl(rnkQ[t], r16);
                const size_t mb = (size_t)rnk * MSGB;
                bf16x4 v4;
                #pragma unroll
                for (int gg = 0; gg < 4; ++gg) v4[gg] = (__bf16)(inv * sh0[t] * acc0[t][gg]);
                *reinterpret_cast<bf16x4*>(msg + mb + 4 * q) = v4;
                if (q < 3) {
                    #pragma unroll
                    for (int gg = 0; gg < 4; ++gg)
                        msg[mb + 16 + 3 * gg + q] =
                            (__bf16)(inv * sh1[t] * acc1[t][gg]);
                }
            } else {
                const size_t ob = (size_t)srcI[t] * MSG;
                #pragma unroll
                for (int gg = 0; gg < 4; ++gg)
                    atomicAdd(&out_acc[ob + 4 * q + gg], inv * sh0[t] * acc0[t][gg]);
                if (q < 3) {
                    #pragma unroll
                    for (int gg = 0; gg < 4; ++gg)
                        atomicAdd(&out_acc[ob + 16 + 3 * gg + q], inv * sh1[t] * acc1[t][gg]);
                }
                if (q == 3) atomicAdd(&cnt[srcI[t]], 1.f);
            }
        }
    };

    // ---- pipelined schedule: gather(g1) issued before fc2(g0) ----
    bf16x8 eafA[2][2], eafB[2][2], hcA[2][2], hcB[2][2];
    int srcA[2], srcB[2], rnkA[2], rnkB[2];
    float sh0A[2], sh1A[2], sh0B[2], sh1B[2];

    GATHER(0, eafA, srcA, rnkA, sh0A, sh1A);
    FC1(eafA, hcA);
    GATHER(1, eafB, srcB, rnkB, sh0B, sh1B);   // loads land under FC2W(0)
    FC2W(0, hcA, srcA, rnkA, sh0A, sh1A);
    FC1(eafB, hcB);
    FC2W(1, hcB, srcB, rnkB, sh0B, sh1B);
}

// ---------------- node gather-reduce: contiguous CSR-ordered msg rows ----------------
__global__ __launch_bounds__(256) void node_reduce(
    const __bf16* __restrict__ msg,
    const int* __restrict__ count,
    const int* __restrict__ base,
    float* __restrict__ out, int N)
{
    const int tid  = threadIdx.x;
    const int w    = tid >> 6;
    const int l    = tid & 63;
    const int slot = l >> 5;
    const int c    = l & 31;
    const int n    = blockIdx.x * 8 + w * 2 + slot;
    if (n >= N || c >= MSG) return;

    const int deg = count[n];
    const size_t b = (size_t)base[n] * MSGB;
    float acc = 0.f;
    int j = 0;
    for (; j + 4 <= deg; j += 4) {
        const float v0 = (float)msg[b + (size_t)(j + 0) * MSGB + c];
        const float v1 = (float)msg[b + (size_t)(j + 1) * MSGB + c];
        const float v2 = (float)msg[b + (size_t)(j + 2) * MSGB + c];
        const float v3 = (float)msg[b + (size_t)(j + 3) * MSGB + c];
        acc += (v0 + v1) + (v2 + v3);
    }
    for (; j < deg; ++j) acc += (float)msg[b + (size_t)j * MSGB + c];
    out[(size_t)n * MSG + c] = acc / fmaxf((float)deg, 1.f);
}

__global__ void finalize_kernel(float* __restrict__ out,
                                const float* __restrict__ cnt, int total)
{
    const int idx = blockIdx.x * blockDim.x + threadIdx.x;
    if (idx < total) {
        const int n = idx / MSG;
        out[idx] = out[idx] / fmaxf(cnt[n], 1.0f);
    }
}

extern "C" void kernel_launch(void* const* d_in, const int* in_sizes, int n_in,
                              void* d_out, int out_size, void* d_ws, size_t ws_size,
                              hipStream_t stream)
{
    const float* node_attr  = (const float*)d_in[0];
    const float* edge_attr  = (const float*)d_in[1];
    const float* edge_sh    = (const float*)d_in[2];
    const float* fc1_w      = (const float*)d_in[3];
    const float* fc1_b      = (const float*)d_in[4];
    const float* fc2_w      = (const float*)d_in[5];
    const float* fc2_b      = (const float*)d_in[6];
    const int*   edge_index = (const int*)d_in[7];

    const int N = in_sizes[0] / NS;
    const int E = in_sizes[1] / NS;
    const int nb = (N + 255) / 256;

    char* ws = (char*)d_ws;
    size_t off = 0;
    auto take = [&](size_t bytes) { off = (off + 255) & ~(size_t)255;
                                    size_t o = off; off += bytes; return o; };
    const size_t o_pk1    = take(PK1_ELEMS * 2);
    const size_t o_pk2    = take(PK2_ELEMS * 2);
    const size_t o_count  = take((size_t)N * 4);
    const size_t o_gctr   = take(256);             // adjacent to count -> one memset
    const size_t o_base   = take((size_t)N * 4);
    const size_t o_cnt    = take((size_t)N * 4);   // MODE1 fallback only
    const size_t o_pos    = take((size_t)E * 4);
    const size_t o_msg    = take((size_t)E * MSGB * 2);
    const bool csr_ok = (off <= ws_size);

    __bf16* pk1 = (__bf16*)(ws + o_pk1);
    __bf16* pk2 = (__bf16*)(ws + o_pk2);
    int* count  = (int*)(ws + o_count);
    int* pos    = (int*)(ws + o_pos);
    float* out  = (float*)d_out;

    const int egrid = (E + 255) / 256;             // 4 waves x 64 edges per block
    const int hblocks = (E + 255) / 256;

    if (csr_ok) {
        int* gctr   = (int*)(ws + o_gctr);
        int* base   = (int*)(ws + o_base);
        __bf16* msg = (__bf16*)(ws + o_msg);

        // count + gctr contiguous -> single memset
        hipMemsetAsync(ws + o_count, 0, o_gctr - o_count + 256, stream);

        prep_kernel<<<PACK_BLOCKS + hblocks, 256, 0, stream>>>(
            fc1_w, fc1_b, fc2_w, fc2_b, edge_index, pk1, pk2, count, pos, E);
        scan_atomic<<<nb, 256, 0, stream>>>(count, base, gctr, N);

        edge_mfma_kernel<0><<<egrid, 256, 0, stream>>>(node_attr, edge_attr, edge_sh,
                                                       edge_index, base, pos,
                                                       pk1, pk2, msg, nullptr, nullptr, E);

        node_reduce<<<(N + 7) / 8, 256, 0, stream>>>(msg, count, base, out, N);
    } else {
        float* cntp = (float*)(ws + o_cnt);
        hipMemsetAsync(d_out, 0, (size_t)out_size * sizeof(float), stream);
        hipMemsetAsync(ws + o_count, 0, (size_t)N * 4, stream);
        hipMemsetAsync(cntp, 0, (size_t)N * 4, stream);
        prep_kernel<<<PACK_BLOCKS + hblocks, 256, 0, stream>>>(
            fc1_w, fc1_b, fc2_w, fc2_b, edge_index, pk1, pk2, count, pos, E);
        edge_mfma_kernel<1><<<egrid, 256, 0, stream>>>(node_attr, edge_attr, edge_sh,
                                                       edge_index, nullptr, nullptr,
                                                       pk1, pk2, nullptr, out, cntp, E);
        const int total = N * MSG;
        finalize_kernel<<<(total + 255) / 256, 256, 0, stream>>>(out, cntp, total);
    }
}

// Round 19
// 122.297 us; speedup vs baseline: 1.1428x; 1.1428x over previous
//
#include <hip/hip_runtime.h>

#define NS   16
#define NV   4
#define FEAT 48          // N_EDGE_FEAT
#define WN   320         // W_NUMEL
#define MSG  28          // logical message width (fp32 out)
#define MSGB 32          // bf16 msg row stride (elements) -> 64 B rows

typedef __bf16 bf16x8 __attribute__((ext_vector_type(8)));
typedef __bf16 bf16x4 __attribute__((ext_vector_type(4)));
typedef float  f32x4  __attribute__((ext_vector_type(4)));

#define PK1_ELEMS (2 * 3 * 64 * 8)    // 3072 bf16
#define PK2_ELEMS (2 * 20 * 64 * 8)   // 20480 bf16
#define PACK_BLOCKS 8

// ---------------- prep: weight packing (blocks 0..7) + histogram WITH positions ----------------
// pos[e] = this edge's arrival index within its src group (the histogram atomic's
// return value). Lets the edge kernel compute its CSR slot with plain loads only —
// zero atomics on the critical kernel (r7<->r9 A/B: inline cursor atomic cost ~13us).
__global__ void prep_kernel(const float* __restrict__ fc1_w, const float* __restrict__ fc1_b,
                            const float* __restrict__ fc2_w, const float* __restrict__ fc2_b,
                            const int* __restrict__ src,
                            __bf16* __restrict__ pk1, __bf16* __restrict__ pk2,
                            int* __restrict__ count, int* __restrict__ pos, int E)
{
    const int tid = threadIdx.x;
    if (blockIdx.x < PACK_BLOCKS) {
        const int idx = blockIdx.x * 256 + tid;
        const int stride = PACK_BLOCKS * 256;
        for (int i = idx; i < PK1_ELEMS; i += stride) {
            const int j = i & 7, l = (i >> 3) & 63, f = i >> 9;   // f = p*3 + nt
            const int nt = f % 3, p = f / 3;
            const int q = l >> 4, col = 16 * nt + (l & 15);
            float v;
            if (p == 0) {
                const int k = (j < 4) ? (4 * q + j) : (16 + 4 * q + j - 4);
                v = fc1_w[k * FEAT + col];
            } else if (j < 4) {
                v = fc1_w[(32 + 4 * q + j) * FEAT + col];
            } else {
                v = (j == 4 && q == 0) ? fc1_b[col] : 0.f;
            }
            pk1[i] = (__bf16)v;
        }
        for (int i = idx; i < PK2_ELEMS; i += stride) {
            const int j = i & 7, l = (i >> 3) & 63, f = i >> 9;   // f = p*20 + nt
            const int nt = f % 20, p = f / 20;
            const int q = l >> 4, col = 16 * nt + (l & 15);
            float v;
            if (p == 0) {
                const int k = (j < 4) ? (4 * q + j) : (16 + 4 * q + j - 4);
                v = fc2_w[k * WN + col];
            } else if (j < 4) {
                v = fc2_w[(32 + 4 * q + j) * WN + col];
            } else {
                v = (j == 4 && q == 0) ? fc2_b[col] : 0.f;
            }
            pk2[i] = (__bf16)v;
        }
    } else {
        const int nb = gridDim.x - PACK_BLOCKS;
        for (int e = (blockIdx.x - PACK_BLOCKS) * 256 + tid; e < E; e += nb * 256)
            pos[e] = atomicAdd(&count[src[e]], 1);
    }
}

// ---------------- CSR scan (two-level, deterministic) ----------------
__global__ void scan_block(const int* __restrict__ in, int* __restrict__ outExcl,
                           int* __restrict__ bsum, int n)
{
    __shared__ int s[256];
    const int tid = threadIdx.x;
    const int i = blockIdx.x * 256 + tid;
    int v = (i < n) ? in[i] : 0;
    int acc = v;
    s[tid] = acc;
    __syncthreads();
    #pragma unroll
    for (int off = 1; off < 256; off <<= 1) {
        int t = (tid >= off) ? s[tid - off] : 0;
        __syncthreads();
        acc += t;
        s[tid] = acc;
        __syncthreads();
    }
    if (i < n) outExcl[i] = acc - v;
    if (tid == 255) bsum[blockIdx.x] = acc;
}

// ---------------- fused edge compute: swapped-operand MFMA, ZERO atomics ----------------
// r12 structure; rank = base[src] + boff[src>>8] + pos[e] — all plain loads (pos
// harvested in prep's histogram). x in wave-private LDS (r6 lesson: dynamically
// indexed operand must live in LDS, not registers). (256,7): 36 VGPR, no spill.
// This kernel is at its latency floor: all resource levers (more tiles/wave, weight
// staging to LDS, occupancy caps, prefetch, pipelined gather) measured and refuted
// (r10/r11/r12/r13/r14/r18 — each either spills past ~40 VGPR or trades occupancy).
// MODE 0: write bf16 msg row at rank. MODE 1: fp32 atomics into out + cnt.
template<int MODE>
__global__ __launch_bounds__(256, 7) void edge_mfma_kernel(
    const float* __restrict__ node_attr,
    const float* __restrict__ edge_attr,
    const float* __restrict__ edge_sh,
    const int*   __restrict__ edge_index,
    const int*   __restrict__ base,    // MODE 0
    const int*   __restrict__ boff,    // MODE 0
    const int*   __restrict__ pos,     // MODE 0
    const __bf16* __restrict__ pk1,
    const __bf16* __restrict__ pk2,
    __bf16* __restrict__ msg,      // MODE 0
    float*  __restrict__ out_acc,  // MODE 1
    float*  __restrict__ cnt,      // MODE 1
    int E)
{
    __shared__ float sX[4][32][20];    // wave-private; row stride 80 B (16B-aligned)

    const int tid = threadIdx.x;
    const int w   = tid >> 6;
    const int l   = tid & 63;
    const int q   = l >> 4;
    const int r16 = l & 15;
    const int e0  = (blockIdx.x * 4 + w) * 32;    // 32 edges per wave (2 tiles)

    const float4 z4 = make_float4(0.f, 0.f, 0.f, 0.f);
    const float bias1 = (q == 0) ? 1.f : 0.f;

    // fc1 weight frags (register-resident, shared by both tiles)
    bf16x8 w1f[2][3];
    #pragma unroll
    for (int p = 0; p < 2; ++p)
        #pragma unroll
        for (int nt = 0; nt < 3; ++nt)
            w1f[p][nt] = *reinterpret_cast<const bf16x8*>(pk1 + ((size_t)(p * 3 + nt) * 64 + l) * 8);

    // ---- gather ea B-frags (lane supplies feats 4q+j of edge r16); x -> LDS ----
    bf16x8 eaf[2][2];
    int   srcI[2], rnkQ[2];
    bool  evt[2];
    float sh0[2], sh1[2];
    #pragma unroll
    for (int t = 0; t < 2; ++t) {
        const int e = e0 + 16 * t + r16;
        const bool ev = (e < E);
        evt[t] = ev;
        srcI[t] = ev ? edge_index[e] : 0;
        const int dstI = ev ? edge_index[E + e] : 0;

        // CSR slot from plain loads (no atomic): q==0 lanes gather, shfl at write
        rnkQ[t] = 0;
        if (MODE == 0 && q == 0 && ev) {
            const int s = srcI[t];
            rnkQ[t] = base[s] + boff[s >> 8] + pos[e];
        }

        float4 ea4 = z4, sa4 = z4, da4 = z4;
        if (ev) {
            ea4 = *reinterpret_cast<const float4*>(edge_attr + (size_t)e * NS + 4 * q);
            sa4 = *reinterpret_cast<const float4*>(node_attr + (size_t)srcI[t] * NS + 4 * q);
            da4 = *reinterpret_cast<const float4*>(node_attr + (size_t)dstI * NS + 4 * q);
        }
        // lane (q, r16) owns x[4q..4q+3] of edge 16t+r16 -> one b128 LDS write
        *reinterpret_cast<f32x4*>(&sX[w][16 * t + r16][4 * q]) =
            f32x4{da4.x, da4.y, da4.z, da4.w};

        bf16x8 f0, f1;
        f0[0]=(__bf16)ea4.x; f0[1]=(__bf16)ea4.y; f0[2]=(__bf16)ea4.z; f0[3]=(__bf16)ea4.w;
        f0[4]=(__bf16)sa4.x; f0[5]=(__bf16)sa4.y; f0[6]=(__bf16)sa4.z; f0[7]=(__bf16)sa4.w;
        f1[0]=(__bf16)da4.x; f1[1]=(__bf16)da4.y; f1[2]=(__bf16)da4.z; f1[3]=(__bf16)da4.w;
        f1[4]=(__bf16)bias1; f1[5]=(__bf16)0.f; f1[6]=(__bf16)0.f; f1[7]=(__bf16)0.f;
        eaf[t][0] = f0;
        eaf[t][1] = f1;
        sh0[t] = ev ? edge_sh[(size_t)e * 9] : 0.f;
        sh1[t] = (ev && q < 3) ? edge_sh[(size_t)e * 9 + 1 + q] : 0.f;
    }

    // ---- fc1 (swapped): D[row=feat 16nt+4q+g][col=edge r16]; relu; repack to hc frags ----
    bf16x8 hc[2][2];
    #pragma unroll
    for (int t = 0; t < 2; ++t) {
        f32x4 h0 = {0.f,0.f,0.f,0.f}, h1 = {0.f,0.f,0.f,0.f}, h2 = {0.f,0.f,0.f,0.f};
        h0 = __builtin_amdgcn_mfma_f32_16x16x32_bf16(w1f[0][0], eaf[t][0], h0, 0, 0, 0);
        h0 = __builtin_amdgcn_mfma_f32_16x16x32_bf16(w1f[1][0], eaf[t][1], h0, 0, 0, 0);
        h1 = __builtin_amdgcn_mfma_f32_16x16x32_bf16(w1f[0][1], eaf[t][0], h1, 0, 0, 0);
        h1 = __builtin_amdgcn_mfma_f32_16x16x32_bf16(w1f[1][1], eaf[t][1], h1, 0, 0, 0);
        h2 = __builtin_amdgcn_mfma_f32_16x16x32_bf16(w1f[0][2], eaf[t][0], h2, 0, 0, 0);
        h2 = __builtin_amdgcn_mfma_f32_16x16x32_bf16(w1f[1][2], eaf[t][1], h2, 0, 0, 0);
        bf16x8 c0, c1;
        #pragma unroll
        for (int g = 0; g < 4; ++g) {
            c0[g]     = (__bf16)fmaxf(h0[g], 0.f);   // feats  4q+g   (nt=0)
            c0[4 + g] = (__bf16)fmaxf(h1[g], 0.f);   // feats 16+4q+g (nt=1)
            c1[g]     = (__bf16)fmaxf(h2[g], 0.f);   // feats 32+4q+g (nt=2)
        }
        c1[4] = (__bf16)bias1;                       // k=48 constant-1 (bias row)
        c1[5] = (__bf16)0.f; c1[6] = (__bf16)0.f; c1[7] = (__bf16)0.f;
        hc[t][0] = c0;
        hc[t][1] = c1;
    }

    // ---- fc2 (swapped) + fused tensor product (x from wave-private LDS) ----
    f32x4 acc0[2] = {{0.f,0.f,0.f,0.f},{0.f,0.f,0.f,0.f}};
    f32x4 acc1[2] = {{0.f,0.f,0.f,0.f},{0.f,0.f,0.f,0.f}};
    #pragma unroll 4
    for (int nt2 = 0; nt2 < 20; ++nt2) {
        const bf16x8 wf0 = *reinterpret_cast<const bf16x8*>(pk2 + ((size_t)(0 * 20 + nt2) * 64 + l) * 8);
        const bf16x8 wf1 = *reinterpret_cast<const bf16x8*>(pk2 + ((size_t)(1 * 20 + nt2) * 64 + l) * 8);
        #pragma unroll
        for (int t = 0; t < 2; ++t) {
            f32x4 d = {0.f,0.f,0.f,0.f};
            d = __builtin_amdgcn_mfma_f32_16x16x32_bf16(wf0, hc[t][0], d, 0, 0, 0);
            d = __builtin_amdgcn_mfma_f32_16x16x32_bf16(wf1, hc[t][1], d, 0, 0, 0);
            // lane holds w[edge r16][wcol = 16*nt2 + 4q+g]
            if (nt2 < 16) {
                // w0[u=nt2][c=4q+g]
                const float xv = sX[w][16 * t + r16][nt2];
                #pragma unroll
                for (int g = 0; g < 4; ++g) acc0[t][g] = fmaf(xv, d[g], acc0[t][g]);
            } else {
                // w1[u=4*(nt2-16)+q][v=g]
                const float xu = sX[w][16 * t + r16][4 * (nt2 - 16) + q];
                #pragma unroll
                for (int g = 0; g < 4; ++g) acc1[t][g] = fmaf(xu, d[g], acc1[t][g]);
            }
        }
    }

    const float inv = 0.25f;   // 1/sqrt(16)

    // out1: reduce partial u-sums across the 4 q-groups (lane bits 4,5)
    #pragma unroll
    for (int t = 0; t < 2; ++t)
        #pragma unroll
        for (int g = 0; g < 4; ++g) {
            float s = acc1[t][g];
            s += __shfl_xor(s, 16);
            s += __shfl_xor(s, 32);
            acc1[t][g] = s;
        }

    #pragma unroll
    for (int t = 0; t < 2; ++t) {
        const int e = e0 + 16 * t + r16;
        if (e >= E) continue;
        if (MODE == 0) {
            const int rnk = __shfl(rnkQ[t], r16);      // broadcast q==0 lanes' slot
            const size_t mb = (size_t)rnk * MSGB;
            bf16x4 v4;
            #pragma unroll
            for (int g = 0; g < 4; ++g) v4[g] = (__bf16)(inv * sh0[t] * acc0[t][g]);
            *reinterpret_cast<bf16x4*>(msg + mb + 4 * q) = v4;                 // cols 4q..4q+3
            if (q < 3) {
                #pragma unroll
                for (int g = 0; g < 4; ++g)
                    msg[mb + 16 + 3 * g + q] =
                        (__bf16)(inv * sh1[t] * acc1[t][g]);                   // m=q, v=g
            }
        } else {
            const size_t ob = (size_t)srcI[t] * MSG;
            #pragma unroll
            for (int g = 0; g < 4; ++g)
                atomicAdd(&out_acc[ob + 4 * q + g], inv * sh0[t] * acc0[t][g]);
            if (q < 3) {
                #pragma unroll
                for (int g = 0; g < 4; ++g)
                    atomicAdd(&out_acc[ob + 16 + 3 * g + q], inv * sh1[t] * acc1[t][g]);
            }
            if (q == 3) atomicAdd(&cnt[srcI[t]], 1.f);
        }
    }
}

// ---------------- node gather-reduce: contiguous CSR-ordered msg rows ----------------
__global__ __launch_bounds__(256) void node_reduce(
    const __bf16* __restrict__ msg,
    const int* __restrict__ count,
    const int* __restrict__ base,
    const int* __restrict__ boff,
    float* __restrict__ out, int N)
{
    const int tid  = threadIdx.x;
    const int w    = tid >> 6;
    const int l    = tid & 63;
    const int slot = l >> 5;
    const int c    = l & 31;
    const int n    = blockIdx.x * 8 + w * 2 + slot;
    if (n >= N || c >= MSG) return;

    const int deg = count[n];
    const size_t b = (size_t)(base[n] + boff[n >> 8]) * MSGB;
    float acc = 0.f;
    int j = 0;
    for (; j + 4 <= deg; j += 4) {
        const float v0 = (float)msg[b + (size_t)(j + 0) * MSGB + c];
        const float v1 = (float)msg[b + (size_t)(j + 1) * MSGB + c];
        const float v2 = (float)msg[b + (size_t)(j + 2) * MSGB + c];
        const float v3 = (float)msg[b + (size_t)(j + 3) * MSGB + c];
        acc += (v0 + v1) + (v2 + v3);
    }
    for (; j < deg; ++j) acc += (float)msg[b + (size_t)j * MSGB + c];
    out[(size_t)n * MSG + c] = acc / fmaxf((float)deg, 1.f);
}

__global__ void finalize_kernel(float* __restrict__ out,
                                const float* __restrict__ cnt, int total)
{
    const int idx = blockIdx.x * blockDim.x + threadIdx.x;
    if (idx < total) {
        const int n = idx / MSG;
        out[idx] = out[idx] / fmaxf(cnt[n], 1.0f);
    }
}

extern "C" void kernel_launch(void* const* d_in, const int* in_sizes, int n_in,
                              void* d_out, int out_size, void* d_ws, size_t ws_size,
                              hipStream_t stream)
{
    const float* node_attr  = (const float*)d_in[0];
    const float* edge_attr  = (const float*)d_in[1];
    const float* edge_sh    = (const float*)d_in[2];
    const float* fc1_w      = (const float*)d_in[3];
    const float* fc1_b      = (const float*)d_in[4];
    const float* fc2_w      = (const float*)d_in[5];
    const float* fc2_b      = (const float*)d_in[6];
    const int*   edge_index = (const int*)d_in[7];

    const int N = in_sizes[0] / NS;
    const int E = in_sizes[1] / NS;
    const int nb = (N + 255) / 256;

    char* ws = (char*)d_ws;
    size_t off = 0;
    auto take = [&](size_t bytes) { off = (off + 255) & ~(size_t)255;
                                    size_t o = off; off += bytes; return o; };
    const size_t o_pk1    = take(PK1_ELEMS * 2);
    const size_t o_pk2    = take(PK2_ELEMS * 2);
    const size_t o_count  = take((size_t)N * 4);
    const size_t o_base   = take((size_t)N * 4);
    const size_t o_cnt    = take((size_t)N * 4);   // MODE1 fallback only
    const size_t o_bsum   = take(1024);
    const size_t o_boff   = take(1024);
    const size_t o_tot    = take(1024);     // scratch bsum-out for 2nd scan (distinct from boff)
    const size_t o_pos    = take((size_t)E * 4);
    const size_t o_msg    = take((size_t)E * MSGB * 2);
    const bool csr_ok = (off <= ws_size) && (nb <= 256);

    __bf16* pk1 = (__bf16*)(ws + o_pk1);
    __bf16* pk2 = (__bf16*)(ws + o_pk2);
    int* count  = (int*)(ws + o_count);
    int* pos    = (int*)(ws + o_pos);
    float* out  = (float*)d_out;

    const int egrid = (E + 127) / 128;
    const int hblocks = (E + 255) / 256;

    if (csr_ok) {
        int* base   = (int*)(ws + o_base);
        int* bsum   = (int*)(ws + o_bsum);
        int* boff   = (int*)(ws + o_boff);
        int* tot    = (int*)(ws + o_tot);
        __bf16* msg = (__bf16*)(ws + o_msg);

        hipMemsetAsync(count, 0, (size_t)N * 4, stream);

        prep_kernel<<<PACK_BLOCKS + hblocks, 256, 0, stream>>>(
            fc1_w, fc1_b, fc2_w, fc2_b, edge_index, pk1, pk2, count, pos, E);
        scan_block<<<nb, 256, 0, stream>>>(count, base, bsum, N);
        scan_block<<<1, 256, 0, stream>>>(bsum, boff, tot, nb);

        edge_mfma_kernel<0><<<egrid, 256, 0, stream>>>(node_attr, edge_attr, edge_sh,
                                                       edge_index, base, boff, pos,
                                                       pk1, pk2, msg, nullptr, nullptr, E);

        node_reduce<<<(N + 7) / 8, 256, 0, stream>>>(msg, count, base, boff, out, N);
    } else {
        float* cntp = (float*)(ws + o_cnt);
        hipMemsetAsync(d_out, 0, (size_t)out_size * sizeof(float), stream);
        hipMemsetAsync(ws + o_count, 0, (size_t)N * 4, stream);
        hipMemsetAsync(cntp, 0, (size_t)N * 4, stream);
        prep_kernel<<<PACK_BLOCKS + hblocks, 256, 0, stream>>>(
            fc1_w, fc1_b, fc2_w, fc2_b, edge_index, pk1, pk2, count, pos, E);
        edge_mfma_kernel<1><<<egrid, 256, 0, stream>>>(node_attr, edge_attr, edge_sh,
                                                       edge_index, nullptr, nullptr, nullptr,
                                                       pk1, pk2, nullptr, out, cntp, E);
        const int total = N * MSG;
        finalize_kernel<<<(total + 255) / 256, 256, 0, stream>>>(out, cntp, total);
    }
}

// Round 20
// 122.075 us; speedup vs baseline: 1.1449x; 1.0018x over previous
//
#include <hip/hip_runtime.h>

#define NS   16
#define NV   4
#define FEAT 48          // N_EDGE_FEAT
#define WN   320         // W_NUMEL
#define MSG  28          // logical message width (fp32 out)
#define MSGB 32          // bf16 msg row stride (elements) -> 64 B rows

typedef __bf16 bf16x8 __attribute__((ext_vector_type(8)));
typedef __bf16 bf16x4 __attribute__((ext_vector_type(4)));
typedef float  f32x4  __attribute__((ext_vector_type(4)));

#define PK1_ELEMS (2 * 3 * 64 * 8)    // 3072 bf16
#define PK2_ELEMS (2 * 20 * 64 * 8)   // 20480 bf16
#define PACK_BLOCKS 8

// ---------------- prep: weight packing (blocks 0..7) + histogram WITH positions ----------------
// pos[e] = this edge's arrival index within its src group (the histogram atomic's
// return value). Lets the edge kernel compute its CSR slot with plain loads only —
// zero atomics on the critical kernel (r7<->r9 A/B: inline cursor atomic cost ~13us).
__global__ void prep_kernel(const float* __restrict__ fc1_w, const float* __restrict__ fc1_b,
                            const float* __restrict__ fc2_w, const float* __restrict__ fc2_b,
                            const int* __restrict__ src,
                            __bf16* __restrict__ pk1, __bf16* __restrict__ pk2,
                            int* __restrict__ count, int* __restrict__ pos, int E)
{
    const int tid = threadIdx.x;
    if (blockIdx.x < PACK_BLOCKS) {
        const int idx = blockIdx.x * 256 + tid;
        const int stride = PACK_BLOCKS * 256;
        for (int i = idx; i < PK1_ELEMS; i += stride) {
            const int j = i & 7, l = (i >> 3) & 63, f = i >> 9;   // f = p*3 + nt
            const int nt = f % 3, p = f / 3;
            const int q = l >> 4, col = 16 * nt + (l & 15);
            float v;
            if (p == 0) {
                const int k = (j < 4) ? (4 * q + j) : (16 + 4 * q + j - 4);
                v = fc1_w[k * FEAT + col];
            } else if (j < 4) {
                v = fc1_w[(32 + 4 * q + j) * FEAT + col];
            } else {
                v = (j == 4 && q == 0) ? fc1_b[col] : 0.f;
            }
            pk1[i] = (__bf16)v;
        }
        for (int i = idx; i < PK2_ELEMS; i += stride) {
            const int j = i & 7, l = (i >> 3) & 63, f = i >> 9;   // f = p*20 + nt
            const int nt = f % 20, p = f / 20;
            const int q = l >> 4, col = 16 * nt + (l & 15);
            float v;
            if (p == 0) {
                const int k = (j < 4) ? (4 * q + j) : (16 + 4 * q + j - 4);
                v = fc2_w[k * WN + col];
            } else if (j < 4) {
                v = fc2_w[(32 + 4 * q + j) * WN + col];
            } else {
                v = (j == 4 && q == 0) ? fc2_b[col] : 0.f;
            }
            pk2[i] = (__bf16)v;
        }
    } else {
        const int nb = gridDim.x - PACK_BLOCKS;
        for (int e = (blockIdx.x - PACK_BLOCKS) * 256 + tid; e < E; e += nb * 256)
            pos[e] = atomicAdd(&count[src[e]], 1);
    }
}

// ---------------- CSR scan (two-level, deterministic) ----------------
__global__ void scan_block(const int* __restrict__ in, int* __restrict__ outExcl,
                           int* __restrict__ bsum, int n)
{
    __shared__ int s[256];
    const int tid = threadIdx.x;
    const int i = blockIdx.x * 256 + tid;
    int v = (i < n) ? in[i] : 0;
    int acc = v;
    s[tid] = acc;
    __syncthreads();
    #pragma unroll
    for (int off = 1; off < 256; off <<= 1) {
        int t = (tid >= off) ? s[tid - off] : 0;
        __syncthreads();
        acc += t;
        s[tid] = acc;
        __syncthreads();
    }
    if (i < n) outExcl[i] = acc - v;
    if (tid == 255) bsum[blockIdx.x] = acc;
}

// ---------------- fused edge compute: swapped-operand MFMA, ZERO atomics, setprio ----------------
// r19 structure + s_setprio(1/0) around the MFMA clusters (T5, isolated this round:
// r8 only tested it bundled with a spill-inducing reg cap). Mechanism: waves here are
// barrier-free and independently phased (gather vs fc1 vs fc2), so boosting the
// MFMA-issuing wave's priority lets it clear its compute phase while siblings issue
// memory — the regime where T5 measured +4-7% (attn); null in lockstep GEMM.
// MODE 0: write bf16 msg row at rank = base[src]+boff[src>>8]+pos[e]. MODE 1: atomics.
template<int MODE>
__global__ __launch_bounds__(256, 7) void edge_mfma_kernel(
    const float* __restrict__ node_attr,
    const float* __restrict__ edge_attr,
    const float* __restrict__ edge_sh,
    const int*   __restrict__ edge_index,
    const int*   __restrict__ base,    // MODE 0
    const int*   __restrict__ boff,    // MODE 0
    const int*   __restrict__ pos,     // MODE 0
    const __bf16* __restrict__ pk1,
    const __bf16* __restrict__ pk2,
    __bf16* __restrict__ msg,      // MODE 0
    float*  __restrict__ out_acc,  // MODE 1
    float*  __restrict__ cnt,      // MODE 1
    int E)
{
    __shared__ float sX[4][32][20];    // wave-private; row stride 80 B (16B-aligned)

    const int tid = threadIdx.x;
    const int w   = tid >> 6;
    const int l   = tid & 63;
    const int q   = l >> 4;
    const int r16 = l & 15;
    const int e0  = (blockIdx.x * 4 + w) * 32;    // 32 edges per wave (2 tiles)

    const float4 z4 = make_float4(0.f, 0.f, 0.f, 0.f);
    const float bias1 = (q == 0) ? 1.f : 0.f;

    // fc1 weight frags (register-resident, shared by both tiles)
    bf16x8 w1f[2][3];
    #pragma unroll
    for (int p = 0; p < 2; ++p)
        #pragma unroll
        for (int nt = 0; nt < 3; ++nt)
            w1f[p][nt] = *reinterpret_cast<const bf16x8*>(pk1 + ((size_t)(p * 3 + nt) * 64 + l) * 8);

    // ---- gather ea B-frags (lane supplies feats 4q+j of edge r16); x -> LDS ----
    bf16x8 eaf[2][2];
    int   srcI[2], rnkQ[2];
    bool  evt[2];
    float sh0[2], sh1[2];
    #pragma unroll
    for (int t = 0; t < 2; ++t) {
        const int e = e0 + 16 * t + r16;
        const bool ev = (e < E);
        evt[t] = ev;
        srcI[t] = ev ? edge_index[e] : 0;
        const int dstI = ev ? edge_index[E + e] : 0;

        // CSR slot from plain loads (no atomic): q==0 lanes gather, shfl at write
        rnkQ[t] = 0;
        if (MODE == 0 && q == 0 && ev) {
            const int s = srcI[t];
            rnkQ[t] = base[s] + boff[s >> 8] + pos[e];
        }

        float4 ea4 = z4, sa4 = z4, da4 = z4;
        if (ev) {
            ea4 = *reinterpret_cast<const float4*>(edge_attr + (size_t)e * NS + 4 * q);
            sa4 = *reinterpret_cast<const float4*>(node_attr + (size_t)srcI[t] * NS + 4 * q);
            da4 = *reinterpret_cast<const float4*>(node_attr + (size_t)dstI * NS + 4 * q);
        }
        // lane (q, r16) owns x[4q..4q+3] of edge 16t+r16 -> one b128 LDS write
        *reinterpret_cast<f32x4*>(&sX[w][16 * t + r16][4 * q]) =
            f32x4{da4.x, da4.y, da4.z, da4.w};

        bf16x8 f0, f1;
        f0[0]=(__bf16)ea4.x; f0[1]=(__bf16)ea4.y; f0[2]=(__bf16)ea4.z; f0[3]=(__bf16)ea4.w;
        f0[4]=(__bf16)sa4.x; f0[5]=(__bf16)sa4.y; f0[6]=(__bf16)sa4.z; f0[7]=(__bf16)sa4.w;
        f1[0]=(__bf16)da4.x; f1[1]=(__bf16)da4.y; f1[2]=(__bf16)da4.z; f1[3]=(__bf16)da4.w;
        f1[4]=(__bf16)bias1; f1[5]=(__bf16)0.f; f1[6]=(__bf16)0.f; f1[7]=(__bf16)0.f;
        eaf[t][0] = f0;
        eaf[t][1] = f1;
        sh0[t] = ev ? edge_sh[(size_t)e * 9] : 0.f;
        sh1[t] = (ev && q < 3) ? edge_sh[(size_t)e * 9 + 1 + q] : 0.f;
    }

    // ---- fc1 (swapped): D[row=feat 16nt+4q+g][col=edge r16]; relu; repack to hc frags ----
    bf16x8 hc[2][2];
    #pragma unroll
    for (int t = 0; t < 2; ++t) {
        f32x4 h0 = {0.f,0.f,0.f,0.f}, h1 = {0.f,0.f,0.f,0.f}, h2 = {0.f,0.f,0.f,0.f};
        __builtin_amdgcn_s_setprio(1);
        h0 = __builtin_amdgcn_mfma_f32_16x16x32_bf16(w1f[0][0], eaf[t][0], h0, 0, 0, 0);
        h0 = __builtin_amdgcn_mfma_f32_16x16x32_bf16(w1f[1][0], eaf[t][1], h0, 0, 0, 0);
        h1 = __builtin_amdgcn_mfma_f32_16x16x32_bf16(w1f[0][1], eaf[t][0], h1, 0, 0, 0);
        h1 = __builtin_amdgcn_mfma_f32_16x16x32_bf16(w1f[1][1], eaf[t][1], h1, 0, 0, 0);
        h2 = __builtin_amdgcn_mfma_f32_16x16x32_bf16(w1f[0][2], eaf[t][0], h2, 0, 0, 0);
        h2 = __builtin_amdgcn_mfma_f32_16x16x32_bf16(w1f[1][2], eaf[t][1], h2, 0, 0, 0);
        __builtin_amdgcn_s_setprio(0);
        bf16x8 c0, c1;
        #pragma unroll
        for (int g = 0; g < 4; ++g) {
            c0[g]     = (__bf16)fmaxf(h0[g], 0.f);   // feats  4q+g   (nt=0)
            c0[4 + g] = (__bf16)fmaxf(h1[g], 0.f);   // feats 16+4q+g (nt=1)
            c1[g]     = (__bf16)fmaxf(h2[g], 0.f);   // feats 32+4q+g (nt=2)
        }
        c1[4] = (__bf16)bias1;                       // k=48 constant-1 (bias row)
        c1[5] = (__bf16)0.f; c1[6] = (__bf16)0.f; c1[7] = (__bf16)0.f;
        hc[t][0] = c0;
        hc[t][1] = c1;
    }

    // ---- fc2 (swapped) + fused tensor product (x from wave-private LDS) ----
    f32x4 acc0[2] = {{0.f,0.f,0.f,0.f},{0.f,0.f,0.f,0.f}};
    f32x4 acc1[2] = {{0.f,0.f,0.f,0.f},{0.f,0.f,0.f,0.f}};
    #pragma unroll 4
    for (int nt2 = 0; nt2 < 20; ++nt2) {
        const bf16x8 wf0 = *reinterpret_cast<const bf16x8*>(pk2 + ((size_t)(0 * 20 + nt2) * 64 + l) * 8);
        const bf16x8 wf1 = *reinterpret_cast<const bf16x8*>(pk2 + ((size_t)(1 * 20 + nt2) * 64 + l) * 8);
        __builtin_amdgcn_s_setprio(1);
        f32x4 d0 = {0.f,0.f,0.f,0.f}, d1 = {0.f,0.f,0.f,0.f};
        d0 = __builtin_amdgcn_mfma_f32_16x16x32_bf16(wf0, hc[0][0], d0, 0, 0, 0);
        d0 = __builtin_amdgcn_mfma_f32_16x16x32_bf16(wf1, hc[0][1], d0, 0, 0, 0);
        d1 = __builtin_amdgcn_mfma_f32_16x16x32_bf16(wf0, hc[1][0], d1, 0, 0, 0);
        d1 = __builtin_amdgcn_mfma_f32_16x16x32_bf16(wf1, hc[1][1], d1, 0, 0, 0);
        __builtin_amdgcn_s_setprio(0);
        if (nt2 < 16) {
            const float xv0 = sX[w][r16][nt2];
            const float xv1 = sX[w][16 + r16][nt2];
            #pragma unroll
            for (int g = 0; g < 4; ++g) {
                acc0[0][g] = fmaf(xv0, d0[g], acc0[0][g]);
                acc0[1][g] = fmaf(xv1, d1[g], acc0[1][g]);
            }
        } else {
            const float xu0 = sX[w][r16][4 * (nt2 - 16) + q];
            const float xu1 = sX[w][16 + r16][4 * (nt2 - 16) + q];
            #pragma unroll
            for (int g = 0; g < 4; ++g) {
                acc1[0][g] = fmaf(xu0, d0[g], acc1[0][g]);
                acc1[1][g] = fmaf(xu1, d1[g], acc1[1][g]);
            }
        }
    }

    const float inv = 0.25f;   // 1/sqrt(16)

    // out1: reduce partial u-sums across the 4 q-groups (lane bits 4,5)
    #pragma unroll
    for (int t = 0; t < 2; ++t)
        #pragma unroll
        for (int g = 0; g < 4; ++g) {
            float s = acc1[t][g];
            s += __shfl_xor(s, 16);
            s += __shfl_xor(s, 32);
            acc1[t][g] = s;
        }

    #pragma unroll
    for (int t = 0; t < 2; ++t) {
        const int e = e0 + 16 * t + r16;
        if (e >= E) continue;
        if (MODE == 0) {
            const int rnk = __shfl(rnkQ[t], r16);      // broadcast q==0 lanes' slot
            const size_t mb = (size_t)rnk * MSGB;
            bf16x4 v4;
            #pragma unroll
            for (int g = 0; g < 4; ++g) v4[g] = (__bf16)(inv * sh0[t] * acc0[t][g]);
            *reinterpret_cast<bf16x4*>(msg + mb + 4 * q) = v4;                 // cols 4q..4q+3
            if (q < 3) {
                #pragma unroll
                for (int g = 0; g < 4; ++g)
                    msg[mb + 16 + 3 * g + q] =
                        (__bf16)(inv * sh1[t] * acc1[t][g]);                   // m=q, v=g
            }
        } else {
            const size_t ob = (size_t)srcI[t] * MSG;
            #pragma unroll
            for (int g = 0; g < 4; ++g)
                atomicAdd(&out_acc[ob + 4 * q + g], inv * sh0[t] * acc0[t][g]);
            if (q < 3) {
                #pragma unroll
                for (int g = 0; g < 4; ++g)
                    atomicAdd(&out_acc[ob + 16 + 3 * g + q], inv * sh1[t] * acc1[t][g]);
            }
            if (q == 3) atomicAdd(&cnt[srcI[t]], 1.f);
        }
    }
}

// ---------------- node gather-reduce: contiguous CSR-ordered msg rows ----------------
__global__ __launch_bounds__(256) void node_reduce(
    const __bf16* __restrict__ msg,
    const int* __restrict__ count,
    const int* __restrict__ base,
    const int* __restrict__ boff,
    float* __restrict__ out, int N)
{
    const int tid  = threadIdx.x;
    const int w    = tid >> 6;
    const int l    = tid & 63;
    const int slot = l >> 5;
    const int c    = l & 31;
    const int n    = blockIdx.x * 8 + w * 2 + slot;
    if (n >= N || c >= MSG) return;

    const int deg = count[n];
    const size_t b = (size_t)(base[n] + boff[n >> 8]) * MSGB;
    float acc = 0.f;
    int j = 0;
    for (; j + 4 <= deg; j += 4) {
        const float v0 = (float)msg[b + (size_t)(j + 0) * MSGB + c];
        const float v1 = (float)msg[b + (size_t)(j + 1) * MSGB + c];
        const float v2 = (float)msg[b + (size_t)(j + 2) * MSGB + c];
        const float v3 = (float)msg[b + (size_t)(j + 3) * MSGB + c];
        acc += (v0 + v1) + (v2 + v3);
    }
    for (; j < deg; ++j) acc += (float)msg[b + (size_t)j * MSGB + c];
    out[(size_t)n * MSG + c] = acc / fmaxf((float)deg, 1.f);
}

__global__ void finalize_kernel(float* __restrict__ out,
                                const float* __restrict__ cnt, int total)
{
    const int idx = blockIdx.x * blockDim.x + threadIdx.x;
    if (idx < total) {
        const int n = idx / MSG;
        out[idx] = out[idx] / fmaxf(cnt[n], 1.0f);
    }
}

extern "C" void kernel_launch(void* const* d_in, const int* in_sizes, int n_in,
                              void* d_out, int out_size, void* d_ws, size_t ws_size,
                              hipStream_t stream)
{
    const float* node_attr  = (const float*)d_in[0];
    const float* edge_attr  = (const float*)d_in[1];
    const float* edge_sh    = (const float*)d_in[2];
    const float* fc1_w      = (const float*)d_in[3];
    const float* fc1_b      = (const float*)d_in[4];
    const float* fc2_w      = (const float*)d_in[5];
    const float* fc2_b      = (const float*)d_in[6];
    const int*   edge_index = (const int*)d_in[7];

    const int N = in_sizes[0] / NS;
    const int E = in_sizes[1] / NS;
    const int nb = (N + 255) / 256;

    char* ws = (char*)d_ws;
    size_t off = 0;
    auto take = [&](size_t bytes) { off = (off + 255) & ~(size_t)255;
                                    size_t o = off; off += bytes; return o; };
    const size_t o_pk1    = take(PK1_ELEMS * 2);
    const size_t o_pk2    = take(PK2_ELEMS * 2);
    const size_t o_count  = take((size_t)N * 4);
    const size_t o_base   = take((size_t)N * 4);
    const size_t o_cnt    = take((size_t)N * 4);   // MODE1 fallback only
    const size_t o_bsum   = take(1024);
    const size_t o_boff   = take(1024);
    const size_t o_tot    = take(1024);     // scratch bsum-out for 2nd scan (distinct from boff)
    const size_t o_pos    = take((size_t)E * 4);
    const size_t o_msg    = take((size_t)E * MSGB * 2);
    const bool csr_ok = (off <= ws_size) && (nb <= 256);

    __bf16* pk1 = (__bf16*)(ws + o_pk1);
    __bf16* pk2 = (__bf16*)(ws + o_pk2);
    int* count  = (int*)(ws + o_count);
    int* pos    = (int*)(ws + o_pos);
    float* out  = (float*)d_out;

    const int egrid = (E + 127) / 128;
    const int hblocks = (E + 255) / 256;

    if (csr_ok) {
        int* base   = (int*)(ws + o_base);
        int* bsum   = (int*)(ws + o_bsum);
        int* boff   = (int*)(ws + o_boff);
        int* tot    = (int*)(ws + o_tot);
        __bf16* msg = (__bf16*)(ws + o_msg);

        hipMemsetAsync(count, 0, (size_t)N * 4, stream);

        prep_kernel<<<PACK_BLOCKS + hblocks, 256, 0, stream>>>(
            fc1_w, fc1_b, fc2_w, fc2_b, edge_index, pk1, pk2, count, pos, E);
        scan_block<<<nb, 256, 0, stream>>>(count, base, bsum, N);
        scan_block<<<1, 256, 0, stream>>>(bsum, boff, tot, nb);

        edge_mfma_kernel<0><<<egrid, 256, 0, stream>>>(node_attr, edge_attr, edge_sh,
                                                       edge_index, base, boff, pos,
                                                       pk1, pk2, msg, nullptr, nullptr, E);

        node_reduce<<<(N + 7) / 8, 256, 0, stream>>>(msg, count, base, boff, out, N);
    } else {
        float* cntp = (float*)(ws + o_cnt);
        hipMemsetAsync(d_out, 0, (size_t)out_size * sizeof(float), stream);
        hipMemsetAsync(ws + o_count, 0, (size_t)N * 4, stream);
        hipMemsetAsync(cntp, 0, (size_t)N * 4, stream);
        prep_kernel<<<PACK_BLOCKS + hblocks, 256, 0, stream>>>(
            fc1_w, fc1_b, fc2_w, fc2_b, edge_index, pk1, pk2, count, pos, E);
        edge_mfma_kernel<1><<<egrid, 256, 0, stream>>>(node_attr, edge_attr, edge_sh,
                                                       edge_index, nullptr, nullptr, nullptr,
                                                       pk1, pk2, nullptr, out, cntp, E);
        const int total = N * MSG;
        finalize_kernel<<<(total + 255) / 256, 256, 0, stream>>>(out, cntp, total);
    }
}